// Round 5
// baseline (191.562 us; speedup 1.0000x reference)
//
#include <hip/hip_runtime.h>

typedef float    f32x4 __attribute__((ext_vector_type(4)));
typedef _Float16 f16x2 __attribute__((ext_vector_type(2)));
typedef _Float16 f16x4 __attribute__((ext_vector_type(4)));
typedef _Float16 f16x8 __attribute__((ext_vector_type(8)));
typedef int      i32x4 __attribute__((ext_vector_type(4)));

namespace {
constexpr int B_ = 2, L_ = 2048, S_ = 2048, H_ = 16, E_ = 64;
constexpr int MBLK = 128;        // q rows per block (8 waves x 16)
constexpr int NT = 64;           // s-tile width
constexpr int NTILES = S_ / NT;  // 32

#define SCALE2f 0.1803368801111204f /* 0.125 * log2(e), folded into Q */
#define MBIAS2f -1.8033688e8f       /* -1e9 * 0.125 * log2(e): exp2 -> exactly 0 */

// ws layout:
//   [0, 1MiB)        mask bits (u64 per (row, 64-s-chunk))
//   [1MiB, 9MiB)     Kh f16 [b,h,s,e]
//   [9MiB, 17MiB)    Vh f16 [b,h,e,s]
//   [17MiB, 33MiB)   PO1 f32 partial O of s-group 1   (only if nsg=2)
//   [33MiB, +256KiB) RS0 f32 rowsums of s-group 0
//   [.., +256KiB)    RS1 f32 rowsums of s-group 1
constexpr size_t KHOFF  = (size_t)1 << 20;
constexpr size_t VHOFF  = KHOFF + (size_t)B_ * H_ * S_ * E_ * 2;   // 9 MiB
constexpr size_t POOFF  = (size_t)17 << 20;
constexpr size_t RS0OFF = (size_t)33 << 20;
constexpr size_t RS1OFF = RS0OFF + ((size_t)256 << 10);
constexpr size_t WSNEED = RS1OFF + ((size_t)256 << 10);            // 33.5 MiB

__device__ __forceinline__ f16x2 cvt2(float a, float b) {
  return __builtin_bit_cast(f16x2, __builtin_amdgcn_cvt_pkrtz(a, b));
}
__device__ __forceinline__ int pkh(float a, float b) {
  return __builtin_bit_cast(int, __builtin_amdgcn_cvt_pkrtz(a, b));
}
union H8 { f16x8 v; i32x4 i; };
union H4 { f16x4 v; f16x2 h[2]; };

#define GLOAD_LDS16(g, l)                                              \
  __builtin_amdgcn_global_load_lds(                                    \
      (const __attribute__((address_space(1))) void*)(g),              \
      (__attribute__((address_space(3))) void*)(l), 16, 0, 0)
}  // namespace

// ---- fused pre-pass: kcvt [0,2048) | maskpack [2048,4096) | vcvt [4096,5120)
extern "C" __global__ __launch_bounds__(256)
void prep_kernel(const float* __restrict__ Kg, const float* __restrict__ Vg,
                 const float* __restrict__ Mg, _Float16* __restrict__ Kh,
                 _Float16* __restrict__ Vh, unsigned long long* __restrict__ Wb) {
  __shared__ _Float16 T[64][72];
  const int bid = blockIdx.x;
  const int t   = threadIdx.x;

  if (bid < 2048) {
    // K [b,s,h,e] f32 -> Kh [b,h,s,e] f16 (h-gather)
    const int idx = bid * 256 + t;  // 8-e chunk id
    const int j = idx & 7;
    const int h = (idx >> 3) & (H_ - 1);
    const int s = (idx >> 7) & (S_ - 1);
    const int b = idx >> 18;
    const float* src = Kg + ((((size_t)b * S_ + s) * H_ + h) << 6) + j * 8;
    f32x4 x = *(const f32x4*)src, y = *(const f32x4*)(src + 4);
    i32x4 w = {pkh(x[0], x[1]), pkh(x[2], x[3]), pkh(y[0], y[1]), pkh(y[2], y[3])};
    *(i32x4*)(Kh + ((((size_t)b * H_ + h) * S_ + s) << 6) + j * 8) = w;
  } else if (bid < 4096) {
    // mask fp32 -> 1 bit/element; thread: 16 floats (64B coalesced) -> one u16
    const int u = (bid - 2048) * 256 + t;
    const float* src = Mg + (size_t)u * 16;
    unsigned m = 0;
#pragma unroll
    for (int i = 0; i < 4; ++i) {
      f32x4 x = *(const f32x4*)(src + i * 4);
#pragma unroll
      for (int c = 0; c < 4; ++c) m |= (x[c] > 0.5f ? 1u : 0u) << (i * 4 + c);
    }
    ((unsigned short*)Wb)[u] = (unsigned short)m;
  } else {
    // V [b,s,h,e] f32 -> Vh [b,h,e,s] f16 (transpose via LDS)
    const int vb = bid - 4096;  // (b,h,st)
    const int st = vb & 31;
    const int h  = (vb >> 5) & (H_ - 1);
    const int b  = vb >> 9;
    const int sl = t >> 2;
    const int e0 = (t & 3) << 4;
    const float* src = Vg + ((((size_t)b * S_ + st * 64 + sl) * H_ + h) << 6) + e0;
#pragma unroll
    for (int i = 0; i < 4; ++i) {
      f32x4 x = *(const f32x4*)(src + i * 4);
#pragma unroll
      for (int c = 0; c < 4; ++c) T[e0 + i * 4 + c][sl] = (_Float16)x[c];
    }
    __syncthreads();
    const int er = t >> 2;
    const int s0 = (t & 3) << 4;
    _Float16* dst = Vh + (((((size_t)b * H_ + h) << 6) + er) * S_) + st * 64 + s0;
    *(i32x4*)dst       = *(const i32x4*)&T[er][s0];
    *(i32x4*)(dst + 8) = *(const i32x4*)&T[er][s0 + 8];
  }
}

// 8 waves x 16 q-rows (r1 layout, best measured). nsg=2: each (qb,bh) is split
// into 2 blocks over the s-range -> grid 1024, 3 blocks/CU (tri-buffer 48KB),
// independent blocks de-phase so QK/softmax/PV of different blocks overlap.
// PV is lagged one tile (T15): iter t = QK(t) -> PV(t-1) -> softmax(t); PV(t-1)
// is independent of QK(t)'s result so its MFMAs fill the softmax VALU phase.
// Tri-buffer makes the lag race-free: DMA(t+2) (into buf[(t-1)%3]) is issued
// only after the barrier every wave passes *after* finishing PV(t-1).
extern "C" __global__ __launch_bounds__(512, 6)
void fattn_kernel(const float* __restrict__ Qg, const _Float16* __restrict__ Kh,
                  const _Float16* __restrict__ Vh, const unsigned long long* __restrict__ Wb,
                  float* __restrict__ Og, float* __restrict__ PO1,
                  float* __restrict__ RS0, float* __restrict__ RS1, int nsg) {
  // tri-buffer: [buf][row][64], 8 KB each; DMA dest lane-contiguous (no pad),
  // bank safety via XOR-granule swizzle
  __shared__ __align__(16) _Float16 Ks[3][NT][64];
  __shared__ __align__(16) _Float16 Vt[3][E_][64];

  const int tid  = threadIdx.x;
  const int wv   = tid >> 6;   // 0..7
  const int lane = tid & 63;
  const int qd   = lane >> 4;
  const int cl   = lane & 15;
  const int sw   = cl & 7;     // reader swizzle key (row & 7)

  // XCD-locality: bid%8 == bh%8 -> all blocks of one (b,h) on one XCD
  const int bid  = blockIdx.x;
  const int bh   = bid & 31;
  const int rest = bid >> 5;
  const int sg   = rest & (nsg - 1);
  const int qb   = (nsg == 2) ? (rest >> 1) : rest;
  const int h    = bh & (H_ - 1);
  const int b    = bh >> 4;
  const int nts  = (nsg == 2) ? (NTILES / 2) : NTILES;
  const int ts0  = sg * nts;

  const int l0 = qb * MBLK + wv * 16;  // 16 q rows per wave

  // ---- Q fragments (B-operand of S^T = K Q^T), f16, pre-scaled by SCALE2f
  f16x8 qf[2];
  {
    const float* qp = Qg + ((((size_t)b * L_ + (l0 + cl)) * H_ + h) << 6);
#pragma unroll
    for (int kb = 0; kb < 2; ++kb) {
      const int e0 = qd * 8 + kb * 32;
      f32x4 x = *(const f32x4*)(qp + e0);
      f32x4 y = *(const f32x4*)(qp + e0 + 4);
      x *= SCALE2f;
      y *= SCALE2f;
      H8 u;
      u.i = (i32x4){pkh(x[0], x[1]), pkh(x[2], x[3]), pkh(y[0], y[1]), pkh(y[2], y[3])};
      qf[kb] = u.v;
    }
  }

  // ---- DMA lane constants: lane = 8*row_local + granule_slot
  const int rl  = lane >> 3;       // row within wave's 8-row slab (0..7)
  const int gsl = lane & 7;        // granule slot in LDS row
  const int gsw = gsl ^ rl;        // swizzled source granule (row&7 == rl)
  const _Float16* khb = Kh + ((((size_t)b * H_ + h) * S_) << 6);          // [s][e]
  const _Float16* vhb = Vh + ((((size_t)b * H_ + h) << 6) * (size_t)S_);  // [e][s]

  const unsigned long long* wbp = Wb + (((size_t)b * L_ + (l0 + cl)) << 5) + ts0;

  // stage one tile's K+V (16 B/lane, 8 rows/wave each)
  auto dma = [&](int buf, int t) {
    const int ts = ts0 + t;
    const int r0 = wv * 8;
    const _Float16* ksrc = khb + (((size_t)(ts * 64 + r0 + rl)) << 6) + gsw * 8;
    GLOAD_LDS16(ksrc, &Ks[buf][r0][0]);
    const _Float16* vsrc = vhb + (size_t)(r0 + rl) * S_ + ts * 64 + gsw * 8;
    GLOAD_LDS16(vsrc, &Vt[buf][r0][0]);
  };

  const f32x4 zero4 = {0.f, 0.f, 0.f, 0.f};
  f32x4 acc[4];
#pragma unroll
  for (int et = 0; et < 4; ++et) acc[et] = zero4;
  f32x4 rs4 = zero4;
  f16x4 pa[4];  // lag-1 P fragments: written by softmax(t), consumed by PV at t+1

  dma(0, 0);
  unsigned long long mwcur = wbp[0];

  int bc = 0;  // t % 3
  for (int t = 0; t < nts; ++t) {
    __syncthreads();  // drains DMA for buf[bc]; all waves done with PV(t-2)

    const int bn = (bc == 2) ? 0 : bc + 1;
    const int bp = (bc == 0) ? 2 : bc - 1;
    if (t + 1 < nts) dma(bn, t + 1);
    unsigned long long mwnext = 0;
    if (t + 1 < nts) mwnext = wbp[t + 1];

    // ---- S^T = K Q^T  (A: swizzled Ks rows b128; B: pre-scaled Q regs)
    f32x4 sc[4];
#pragma unroll
    for (int nt = 0; nt < 4; ++nt) {
      const _Float16* krow = &Ks[bc][nt * 16 + cl][0];
      const f16x8 a0 = *(const f16x8*)(krow + ((qd ^ sw) << 3));
      const f16x8 a1 = *(const f16x8*)(krow + (((qd + 4) ^ sw) << 3));
      f32x4 c = zero4;
      c = __builtin_amdgcn_mfma_f32_16x16x32_f16(a0, qf[0], c, 0, 0, 0);
      c = __builtin_amdgcn_mfma_f32_16x16x32_f16(a1, qf[1], c, 0, 0, 0);
      sc[nt] = c;  // q = cl, s = (ts0+t)*64 + nt*16 + qd*4 + r
    }

    // ---- O += P(t-1) V(t-1)  (independent of sc -> overlaps softmax below)
    if (t) {
#pragma unroll
      for (int nt = 0; nt < 4; ++nt)
#pragma unroll
        for (int et = 0; et < 4; ++et) {
          const _Float16* vrow = &Vt[bp][et * 16 + cl][0];
          const f16x4 bv = *(const f16x4*)(vrow + ((((2 * nt + (qd >> 1)) ^ sw) << 3) + ((qd & 1) << 2)));
          acc[et] = __builtin_amdgcn_mfma_f32_16x16x16f16(pa[nt], bv, acc[et], 0, 0, 0);
        }
    }

    // ---- softmax numerator for tile t; P into pa for next iteration's PV
    if (mwcur == ~0ull) {  // all-attend fast path (exp2 direct: Q pre-scaled)
#pragma unroll
      for (int nt = 0; nt < 4; ++nt) {
        f32x4 p;
#pragma unroll
        for (int r = 0; r < 4; ++r)
          p[r] = __builtin_amdgcn_exp2f(sc[nt][r]);
        rs4 += p;
        H4 u;
        u.h[0] = cvt2(p[0], p[1]);
        u.h[1] = cvt2(p[2], p[3]);
        pa[nt] = u.v;
      }
    } else {
      const unsigned lo = (unsigned)mwcur;
      const unsigned hi = (unsigned)(mwcur >> 32);
#pragma unroll
      for (int nt = 0; nt < 4; ++nt) {
        const unsigned shm = ((nt < 2) ? lo : hi) >> ((nt & 1) * 16 + qd * 4);
        f32x4 p;
#pragma unroll
        for (int r = 0; r < 4; ++r) {
          const float bias = (shm & (1u << r)) ? 0.f : MBIAS2f;
          p[r] = __builtin_amdgcn_exp2f(sc[nt][r] + bias);
        }
        rs4 += p;
        H4 u;
        u.h[0] = cvt2(p[0], p[1]);
        u.h[1] = cvt2(p[2], p[3]);
        pa[nt] = u.v;
      }
    }

    mwcur = mwnext;
    bc = bn;
  }

  // ---- drain the lagged PV for the final tile
  {
    const int bl = (nts - 1) % 3;
#pragma unroll
    for (int nt = 0; nt < 4; ++nt)
#pragma unroll
      for (int et = 0; et < 4; ++et) {
        const _Float16* vrow = &Vt[bl][et * 16 + cl][0];
        const f16x4 bv = *(const f16x4*)(vrow + ((((2 * nt + (qd >> 1)) ^ sw) << 3) + ((qd & 1) << 2)));
        acc[et] = __builtin_amdgcn_mfma_f32_16x16x16f16(pa[nt], bv, acc[et], 0, 0, 0);
      }
  }

  // ---- epilogue
  float v = rs4[0] + rs4[1] + rs4[2] + rs4[3];
  v += __shfl_xor(v, 16, 64);
  v += __shfl_xor(v, 32, 64);  // every lane: partial row sum for q = cl

  if (nsg == 1) {
#pragma unroll
    for (int r = 0; r < 4; ++r) {
      const float invq = 1.0f / __shfl(v, qd * 4 + r, 64);
      const int l = l0 + qd * 4 + r;
      float* op = Og + ((((size_t)b * H_ + h) * L_ + l) << 6) + cl;
#pragma unroll
      for (int et = 0; et < 4; ++et) op[et * 16] = acc[et][r] * invq;
    }
  } else {
    // store unnormalized partial O + partial rowsums; combine_kernel divides
    float* po        = sg ? PO1 : Og;
    float* rsb       = sg ? RS1 : RS0;
    const size_t rb0 = ((size_t)b * H_ + h) * L_ + l0;
    if (lane < 16) rsb[rb0 + lane] = v;
#pragma unroll
    for (int r = 0; r < 4; ++r) {
      const int l = l0 + qd * 4 + r;
      float* op = po + ((((size_t)b * H_ + h) * L_ + l) << 6) + cl;
#pragma unroll
      for (int et = 0; et < 4; ++et) op[et * 16] = acc[et][r];
    }
  }
}

// O = (Og + PO1) / (RS0 + RS1), elementwise over [B*H*L][64]
extern "C" __global__ __launch_bounds__(256)
void combine_kernel(float* __restrict__ Og, const float* __restrict__ PO1,
                    const float* __restrict__ RS0, const float* __restrict__ RS1) {
  const int idx = blockIdx.x * 256 + threadIdx.x;  // 262144 threads, 16 f32 each
  const int row = idx >> 2;
  const int c0  = (idx & 3) << 4;
  const float inv = 1.0f / (RS0[row] + RS1[row]);
  float* o       = Og  + ((size_t)row << 6) + c0;
  const float* p = PO1 + ((size_t)row << 6) + c0;
#pragma unroll
  for (int i = 0; i < 4; ++i) {
    f32x4 a = *(const f32x4*)(o + i * 4);
    f32x4 q = *(const f32x4*)(p + i * 4);
    f32x4 r = (a + q) * inv;
    *(f32x4*)(o + i * 4) = r;
  }
}

extern "C" void kernel_launch(void* const* d_in, const int* in_sizes, int n_in,
                              void* d_out, int out_size, void* d_ws, size_t ws_size,
                              hipStream_t stream) {
  const float* Q = (const float*)d_in[0];
  const float* K = (const float*)d_in[1];
  const float* V = (const float*)d_in[2];
  const float* M = (const float*)d_in[3];
  float* O = (float*)d_out;
  unsigned long long* Wb = (unsigned long long*)d_ws;
  _Float16* Khp = (_Float16*)((char*)d_ws + KHOFF);
  _Float16* Vhp = (_Float16*)((char*)d_ws + VHOFF);
  float* PO1 = (float*)((char*)d_ws + POOFF);
  float* RS0 = (float*)((char*)d_ws + RS0OFF);
  float* RS1 = (float*)((char*)d_ws + RS1OFF);

  const int nsg = (ws_size >= WSNEED) ? 2 : 1;

  hipLaunchKernelGGL(prep_kernel, dim3(5120), dim3(256), 0, stream, K, V, M, Khp, Vhp, Wb);
  hipLaunchKernelGGL(fattn_kernel, dim3(512 * nsg), dim3(512), 0, stream,
                     Q, Khp, Vhp, Wb, O, PO1, RS0, RS1, nsg);
  if (nsg == 2)
    hipLaunchKernelGGL(combine_kernel, dim3(1024), dim3(256), 0, stream, O, PO1, RS0, RS1);
}

// Round 6
// 163.842 us; speedup vs baseline: 1.1692x; 1.1692x over previous
//
#include <hip/hip_runtime.h>

typedef float    f32x4 __attribute__((ext_vector_type(4)));
typedef _Float16 f16x2 __attribute__((ext_vector_type(2)));
typedef _Float16 f16x4 __attribute__((ext_vector_type(4)));
typedef _Float16 f16x8 __attribute__((ext_vector_type(8)));
typedef int      i32x4 __attribute__((ext_vector_type(4)));

namespace {
constexpr int B_ = 2, L_ = 2048, S_ = 2048, H_ = 16, E_ = 64;
constexpr int MBLK = 128;        // q rows per block (4 waves x 32)
constexpr int NT = 64;           // s-tile width
constexpr int NTILES = S_ / NT;  // 32

#define SCALE2f 0.1803368801111204f /* 0.125 * log2(e), folded into Q */
#define MBIAS2f -1.8033688e8f       /* -1e9 * 0.125 * log2(e): exp2 -> exactly 0 */

// ws layout: [0,1MiB) mask bits | Kh f16 [b,h,s,e] 8.39MB | Vh f16 [b,h,e,s] 8.39MB
constexpr size_t KHOFF = (size_t)1 << 20;
constexpr size_t VHOFF = KHOFF + (size_t)B_ * H_ * S_ * E_ * 2;

__device__ __forceinline__ f16x2 cvt2(float a, float b) {
  return __builtin_bit_cast(f16x2, __builtin_amdgcn_cvt_pkrtz(a, b));
}
__device__ __forceinline__ int pkh(float a, float b) {
  return __builtin_bit_cast(int, __builtin_amdgcn_cvt_pkrtz(a, b));
}
union H8 { f16x8 v; i32x4 i; };
union H4 { f16x4 v; f16x2 h[2]; };

#define GLOAD_LDS16(g, l)                                              \
  __builtin_amdgcn_global_load_lds(                                    \
      (const __attribute__((address_space(1))) void*)(g),              \
      (__attribute__((address_space(3))) void*)(l), 16, 0, 0)
}  // namespace

// ---- fused pre-pass: kcvt [0,2048) | maskpack [2048,4096) | vcvt [4096,5120)
extern "C" __global__ __launch_bounds__(256)
void prep_kernel(const float* __restrict__ Kg, const float* __restrict__ Vg,
                 const float* __restrict__ Mg, _Float16* __restrict__ Kh,
                 _Float16* __restrict__ Vh, unsigned long long* __restrict__ Wb) {
  __shared__ _Float16 T[64][72];
  const int bid = blockIdx.x;
  const int t   = threadIdx.x;

  if (bid < 2048) {
    // K [b,s,h,e] f32 -> Kh [b,h,s,e] f16 (h-gather)
    const int idx = bid * 256 + t;  // 8-e chunk id
    const int j = idx & 7;
    const int h = (idx >> 3) & (H_ - 1);
    const int s = (idx >> 7) & (S_ - 1);
    const int b = idx >> 18;
    const float* src = Kg + ((((size_t)b * S_ + s) * H_ + h) << 6) + j * 8;
    f32x4 x = *(const f32x4*)src, y = *(const f32x4*)(src + 4);
    i32x4 w = {pkh(x[0], x[1]), pkh(x[2], x[3]), pkh(y[0], y[1]), pkh(y[2], y[3])};
    *(i32x4*)(Kh + ((((size_t)b * H_ + h) * S_ + s) << 6) + j * 8) = w;
  } else if (bid < 4096) {
    // mask fp32 -> 1 bit/element; thread: 16 floats (64B coalesced) -> one u16
    const int u = (bid - 2048) * 256 + t;
    const float* src = Mg + (size_t)u * 16;
    unsigned m = 0;
#pragma unroll
    for (int i = 0; i < 4; ++i) {
      f32x4 x = *(const f32x4*)(src + i * 4);
#pragma unroll
      for (int c = 0; c < 4; ++c) m |= (x[c] > 0.5f ? 1u : 0u) << (i * 4 + c);
    }
    ((unsigned short*)Wb)[u] = (unsigned short)m;
  } else {
    // V [b,s,h,e] f32 -> Vh [b,h,e,s] f16 (transpose via LDS)
    const int vb = bid - 4096;  // (b,h,st)
    const int st = vb & 31;
    const int h  = (vb >> 5) & (H_ - 1);
    const int b  = vb >> 9;
    const int sl = t >> 2;
    const int e0 = (t & 3) << 4;
    const float* src = Vg + ((((size_t)b * S_ + st * 64 + sl) * H_ + h) << 6) + e0;
#pragma unroll
    for (int i = 0; i < 4; ++i) {
      f32x4 x = *(const f32x4*)(src + i * 4);
#pragma unroll
      for (int c = 0; c < 4; ++c) T[e0 + i * 4 + c][sl] = (_Float16)x[c];
    }
    __syncthreads();
    const int er = t >> 2;
    const int s0 = (t & 3) << 4;
    _Float16* dst = Vh + (((((size_t)b * H_ + h) << 6) + er) * S_) + st * 64 + s0;
    *(i32x4*)dst       = *(const i32x4*)&T[er][s0];
    *(i32x4*)(dst + 8) = *(const i32x4*)&T[er][s0 + 8];
  }
}

// 4 waves x 32 q-rows (lowest LDS traffic/output) + tri-buffer + counted-vmcnt:
// each region = 5 VMEM (mask u64 + 4 global_load_lds), issued 2 tiles ahead;
// per-tile wait is vmcnt(5) (region t landed, region t+1 in flight) + raw
// s_barrier -- loads ride through the barrier; never drain to 0 in the loop.
// No sched_barrier(0) pins (the r4 regression, m141): memory-clobber asm only
// fences region boundaries; compiler schedules VALU/MFMA freely.
// Tri-buffer race check: region t+2 (issued after barrier t) writes buf
// (t+2)%3 == (t-1)%3; all reads of tile t-1 completed before any wave passed
// barrier t (their MFMA consumers force lgkmcnt waits inside iter t-1).
extern "C" __global__ __launch_bounds__(256, 2)
void fattn_kernel(const float* __restrict__ Qg, const _Float16* __restrict__ Kh,
                  const _Float16* __restrict__ Vh, const unsigned long long* __restrict__ Wb,
                  float* __restrict__ Og) {
  // tri-buffer: [buf][row][64], 8 KB each; DMA dest lane-contiguous (no pad),
  // bank safety via XOR-granule swizzle
  __shared__ __align__(16) _Float16 Ks[3][NT][64];
  __shared__ __align__(16) _Float16 Vt[3][E_][64];

  const int tid  = threadIdx.x;
  const int wv   = tid >> 6;   // 0..3
  const int lane = tid & 63;
  const int qd   = lane >> 4;
  const int cl   = lane & 15;
  const int sw   = cl & 7;     // reader swizzle key (row & 7)

  // XCD-locality: bid%8 == bh%8 -> all 16 q-blocks of one (b,h) on one XCD
  const int bid = blockIdx.x;
  const int qb  = bid >> 5;
  const int bh  = bid & 31;
  const int h   = bh & (H_ - 1);
  const int b   = bh >> 4;

  const int l0 = qb * MBLK + wv * 32;  // 32 q rows per wave (2 m-tiles)

  // ---- Q fragments (B-operand of S^T = K Q^T), f16, pre-scaled by SCALE2f
  f16x8 qf[2][2];
#pragma unroll
  for (int mt = 0; mt < 2; ++mt) {
    const float* qp = Qg + ((((size_t)b * L_ + (l0 + mt * 16 + cl)) * H_ + h) << 6);
#pragma unroll
    for (int kb = 0; kb < 2; ++kb) {
      const int e0 = qd * 8 + kb * 32;
      f32x4 x = *(const f32x4*)(qp + e0);
      f32x4 y = *(const f32x4*)(qp + e0 + 4);
      x *= SCALE2f;
      y *= SCALE2f;
      H8 u;
      u.i = (i32x4){pkh(x[0], x[1]), pkh(x[2], x[3]), pkh(y[0], y[1]), pkh(y[2], y[3])};
      qf[mt][kb] = u.v;
    }
  }

  // ---- DMA lane constants: lane = 8*row_local + granule_slot
  const int rl  = lane >> 3;       // row within wave-iter (0..7)
  const int gsl = lane & 7;        // granule slot in LDS row
  const int gsw = gsl ^ rl;        // swizzled source granule (row&7 == rl)
  const _Float16* khb = Kh + ((((size_t)b * H_ + h) * S_) << 6);          // [s][e]
  const _Float16* vhb = Vh + ((((size_t)b * H_ + h) << 6) * (size_t)S_);  // [e][s]

  const unsigned long long* wbp = Wb + (((size_t)b * L_ + (l0 + cl)) << 5);

  // stage one tile's K+V via global_load_lds (16 B/lane, 2 wave-iters each)
  auto dma = [&](int buf, int t) {
#pragma unroll
    for (int p = 0; p < 2; ++p) {
      const int r0 = p * 32 + wv * 8;
      const _Float16* ksrc = khb + (((size_t)(t * 64 + r0 + rl)) << 6) + gsw * 8;
      GLOAD_LDS16(ksrc, &Ks[buf][r0][0]);
      const _Float16* vsrc = vhb + (size_t)(r0 + rl) * S_ + t * 64 + gsw * 8;
      GLOAD_LDS16(vsrc, &Vt[buf][r0][0]);
    }
  };

  const f32x4 zero4 = {0.f, 0.f, 0.f, 0.f};
  f32x4 acc[2][4];
#pragma unroll
  for (int mt = 0; mt < 2; ++mt)
#pragma unroll
    for (int et = 0; et < 4; ++et) acc[mt][et] = zero4;
  f32x4 rs4[2] = {zero4, zero4};

  // ---- prologue: regions 0 and 1 (5 VMEM each: mask + 4 gload_lds)
  unsigned long long mwcur = wbp[0];
  dma(0, 0);
  asm volatile("" ::: "memory");  // region boundary
  unsigned long long mwnext = wbp[1];
  dma(1, 1);
  asm volatile("" ::: "memory");

  int bc = 0;  // t % 3
  for (int t = 0; t < NTILES; ++t) {
    // region t landed (tile t K,V,mask); region t+1 (5 ops) stays in flight
    if (t < NTILES - 1)
      asm volatile("s_waitcnt vmcnt(5)" ::: "memory");
    else
      asm volatile("s_waitcnt vmcnt(0)" ::: "memory");
    __builtin_amdgcn_s_barrier();

    // region t+2
    unsigned long long mwnext2 = 0;
    const int bn = (bc == 2) ? 0 : bc + 1;
    if (t + 2 < NTILES) {
      const int b2 = (bn == 2) ? 0 : bn + 1;
      mwnext2 = wbp[t + 2];
      dma(b2, t + 2);
    }
    asm volatile("" ::: "memory");  // region boundary

    // ---- S^T = K Q^T  (A: swizzled Ks rows b128; B: pre-scaled Q regs)
    f32x4 sc[4][2];
#pragma unroll
    for (int nt = 0; nt < 4; ++nt) {
      const _Float16* krow = &Ks[bc][nt * 16 + cl][0];
      const f16x8 a0 = *(const f16x8*)(krow + ((qd ^ sw) << 3));
      const f16x8 a1 = *(const f16x8*)(krow + (((qd + 4) ^ sw) << 3));
#pragma unroll
      for (int mt = 0; mt < 2; ++mt) {
        f32x4 c = zero4;
        c = __builtin_amdgcn_mfma_f32_16x16x32_f16(a0, qf[mt][0], c, 0, 0, 0);
        c = __builtin_amdgcn_mfma_f32_16x16x32_f16(a1, qf[mt][1], c, 0, 0, 0);
        sc[nt][mt] = c;  // q = mt*16+cl, s = nt*16 + qd*4 + r
      }
    }

    // ---- softmax numerator; P stays in registers as PV A-frags
    f16x4 pa[2][4];
    if (mwcur == ~0ull) {  // all-attend fast path (Q pre-scaled: exp2 direct)
#pragma unroll
      for (int mt = 0; mt < 2; ++mt)
#pragma unroll
        for (int nt = 0; nt < 4; ++nt) {
          f32x4 p;
#pragma unroll
          for (int r = 0; r < 4; ++r)
            p[r] = __builtin_amdgcn_exp2f(sc[nt][mt][r]);
          rs4[mt] += p;
          H4 u;
          u.h[0] = cvt2(p[0], p[1]);
          u.h[1] = cvt2(p[2], p[3]);
          pa[mt][nt] = u.v;
        }
    } else {
      const unsigned lo = (unsigned)mwcur;
      const unsigned hi = (unsigned)(mwcur >> 32);
#pragma unroll
      for (int mt = 0; mt < 2; ++mt)
#pragma unroll
        for (int nt = 0; nt < 4; ++nt) {
          const unsigned shm = ((nt < 2) ? lo : hi) >> ((nt & 1) * 16 + qd * 4);
          f32x4 p;
#pragma unroll
          for (int r = 0; r < 4; ++r) {
            const float bias = (shm & (1u << r)) ? 0.f : MBIAS2f;
            p[r] = __builtin_amdgcn_exp2f(sc[nt][mt][r] + bias);
          }
          rs4[mt] += p;
          H4 u;
          u.h[0] = cvt2(p[0], p[1]);
          u.h[1] = cvt2(p[2], p[3]);
          pa[mt][nt] = u.v;
        }
    }

    // ---- O += P V  (A: P regs; B: swizzled Vt rows b64, shared across mt)
#pragma unroll
    for (int nt = 0; nt < 4; ++nt)
#pragma unroll
      for (int et = 0; et < 4; ++et) {
        const _Float16* vrow = &Vt[bc][et * 16 + cl][0];
        const f16x4 bv = *(const f16x4*)(vrow + ((((2 * nt + (qd >> 1)) ^ sw) << 3) + ((qd & 1) << 2)));
        acc[0][et] = __builtin_amdgcn_mfma_f32_16x16x16f16(pa[0][nt], bv, acc[0][et], 0, 0, 0);
        acc[1][et] = __builtin_amdgcn_mfma_f32_16x16x16f16(pa[1][nt], bv, acc[1][et], 0, 0, 0);
      }

    mwcur = mwnext;
    mwnext = mwnext2;
    bc = bn;
  }

  // ---- epilogue: row-sum reduce, broadcast inv per q-row, store
#pragma unroll
  for (int mt = 0; mt < 2; ++mt) {
    float v = rs4[mt][0] + rs4[mt][1] + rs4[mt][2] + rs4[mt][3];
    v += __shfl_xor(v, 16, 64);
    v += __shfl_xor(v, 32, 64);  // every lane: sum for q = mt*16 + cl
#pragma unroll
    for (int r = 0; r < 4; ++r) {
      const float invq = 1.0f / __shfl(v, qd * 4 + r, 64);
      const int l = l0 + mt * 16 + qd * 4 + r;
      float* op = Og + ((((size_t)b * H_ + h) * L_ + l) << 6) + cl;
#pragma unroll
      for (int et = 0; et < 4; ++et) op[et * 16] = acc[mt][et][r] * invq;
    }
  }
}

extern "C" void kernel_launch(void* const* d_in, const int* in_sizes, int n_in,
                              void* d_out, int out_size, void* d_ws, size_t ws_size,
                              hipStream_t stream) {
  const float* Q = (const float*)d_in[0];
  const float* K = (const float*)d_in[1];
  const float* V = (const float*)d_in[2];
  const float* M = (const float*)d_in[3];
  float* O = (float*)d_out;
  unsigned long long* Wb = (unsigned long long*)d_ws;              // 1 MiB
  _Float16* Khp = (_Float16*)((char*)d_ws + KHOFF);                // 8.39 MB
  _Float16* Vhp = (_Float16*)((char*)d_ws + VHOFF);                // 8.39 MB

  hipLaunchKernelGGL(prep_kernel, dim3(5120), dim3(256), 0, stream, K, V, M, Khp, Vhp, Wb);
  hipLaunchKernelGGL(fattn_kernel, dim3(B_ * H_ * (L_ / MBLK)), dim3(256), 0, stream,
                     Q, Khp, Vhp, Wb, O);
}

// Round 7
// 159.588 us; speedup vs baseline: 1.2004x; 1.0267x over previous
//
#include <hip/hip_runtime.h>

typedef float    f32x4 __attribute__((ext_vector_type(4)));
typedef _Float16 f16x2 __attribute__((ext_vector_type(2)));
typedef _Float16 f16x4 __attribute__((ext_vector_type(4)));
typedef _Float16 f16x8 __attribute__((ext_vector_type(8)));
typedef int      i32x4 __attribute__((ext_vector_type(4)));

namespace {
constexpr int B_ = 2, L_ = 2048, S_ = 2048, H_ = 16, E_ = 64;
constexpr int MBLK = 128;        // q rows per block (4 waves x 32)
constexpr int NT = 64;           // s-tile width
constexpr int NTILES = S_ / NT;  // 32

#define SCALE2f 0.1803368801111204f /* 0.125 * log2(e), folded into Q */
#define MBIAS2f -1.8033688e8f       /* -1e9 * 0.125 * log2(e): exp2 -> exactly 0 */

// ws layout: [0,1MiB) mask bits | Kh f16 [b,h,s,e] 8.39MB | Vh f16 [b,h,e,s] 8.39MB
// mask bit layout inside each u64 (one 64-s chunk): bit p = 16*(s&3) + (s>>2 & 15)
constexpr size_t KHOFF = (size_t)1 << 20;
constexpr size_t VHOFF = KHOFF + (size_t)B_ * H_ * S_ * E_ * 2;

__device__ __forceinline__ f16x2 cvt2(float a, float b) {
  return __builtin_bit_cast(f16x2, __builtin_amdgcn_cvt_pkrtz(a, b));
}
__device__ __forceinline__ int pkh(float a, float b) {
  return __builtin_bit_cast(int, __builtin_amdgcn_cvt_pkrtz(a, b));
}
union H8 { f16x8 v; i32x4 i; f16x4 h4[2]; };
union H4 { f16x4 v; f16x2 h[2]; };

#define GLOAD_LDS16(g, l)                                              \
  __builtin_amdgcn_global_load_lds(                                    \
      (const __attribute__((address_space(1))) void*)(g),              \
      (__attribute__((address_space(3))) void*)(l), 16, 0, 0)
}  // namespace

// ---- fused pre-pass: kcvt [0,2048) | maskpack [2048,4096) | vcvt [4096,5120)
extern "C" __global__ __launch_bounds__(256)
void prep_kernel(const float* __restrict__ Kg, const float* __restrict__ Vg,
                 const float* __restrict__ Mg, _Float16* __restrict__ Kh,
                 _Float16* __restrict__ Vh, unsigned long long* __restrict__ Wb) {
  __shared__ _Float16 T[64][72];
  const int bid = blockIdx.x;
  const int t   = threadIdx.x;

  if (bid < 2048) {
    // K [b,s,h,e] f32 -> Kh [b,h,s,e] f16 (h-gather)
    const int idx = bid * 256 + t;  // 8-e chunk id
    const int j = idx & 7;
    const int h = (idx >> 3) & (H_ - 1);
    const int s = (idx >> 7) & (S_ - 1);
    const int b = idx >> 18;
    const float* src = Kg + ((((size_t)b * S_ + s) * H_ + h) << 6) + j * 8;
    f32x4 x = *(const f32x4*)src, y = *(const f32x4*)(src + 4);
    i32x4 w = {pkh(x[0], x[1]), pkh(x[2], x[3]), pkh(y[0], y[1]), pkh(y[2], y[3])};
    *(i32x4*)(Kh + ((((size_t)b * H_ + h) * S_ + s) << 6) + j * 8) = w;
  } else if (bid < 4096) {
    // mask fp32 -> bits: fully-coalesced 16B/lane loads + ballot + SALU pack.
    // wave handles 1024 consecutive floats; step k: 256 floats -> 4 u64 words.
    // word bit p = 16*(s&3) + (s>>2): ballot_i bit (16j+a) -> word j bit 16i+a.
    const int wv2   = t >> 6;
    const int lane2 = t & 63;
    const size_t wave_id = (size_t)(bid - 2048) * 4 + wv2;   // [0, 8192)
    const float* mp = Mg + wave_id * 1024 + lane2 * 4;
    unsigned long long* wp = Wb + wave_id * 16;
#pragma unroll
    for (int k = 0; k < 4; ++k) {
      const f32x4 x = *(const f32x4*)(mp + k * 256);
      const unsigned long long b0 = __ballot(x[0] > 0.5f);
      const unsigned long long b1 = __ballot(x[1] > 0.5f);
      const unsigned long long b2 = __ballot(x[2] > 0.5f);
      const unsigned long long b3 = __ballot(x[3] > 0.5f);
      if (lane2 < 4) {
        const int sh = lane2 * 16;
        const unsigned long long w =
            ((b0 >> sh) & 0xFFFFull) | (((b1 >> sh) & 0xFFFFull) << 16) |
            (((b2 >> sh) & 0xFFFFull) << 32) | (((b3 >> sh) & 0xFFFFull) << 48);
        wp[k * 4 + lane2] = w;
      }
    }
  } else {
    // V [b,s,h,e] f32 -> Vh [b,h,e,s] f16 (transpose via LDS)
    const int vb = bid - 4096;  // (b,h,st)
    const int st = vb & 31;
    const int h  = (vb >> 5) & (H_ - 1);
    const int b  = vb >> 9;
    const int sl = t >> 2;
    const int e0 = (t & 3) << 4;
    const float* src = Vg + ((((size_t)b * S_ + st * 64 + sl) * H_ + h) << 6) + e0;
#pragma unroll
    for (int i = 0; i < 4; ++i) {
      f32x4 x = *(const f32x4*)(src + i * 4);
#pragma unroll
      for (int c = 0; c < 4; ++c) T[e0 + i * 4 + c][sl] = (_Float16)x[c];
    }
    __syncthreads();
    const int er = t >> 2;
    const int s0 = (t & 3) << 4;
    _Float16* dst = Vh + (((((size_t)b * H_ + h) << 6) + er) * S_) + st * 64 + s0;
    *(i32x4*)dst       = *(const i32x4*)&T[er][s0];
    *(i32x4*)(dst + 8) = *(const i32x4*)&T[er][s0 + 8];
  }
}

// 4 waves x 32 q-rows + tri-buffer + counted-vmcnt (r6 structure, best measured)
// + PV at mfma_16x16x32 via permuted-k: MFMA sums k in any consistent order, so
// enumerate k-slots as sigma(qd*8+j) = 16*(j>=4) + qd*4 + (j&3). A-frag is then
// exactly concat(pa[2ntp], pa[2ntp+1]) (already lane-resident from the QK
// C-layout) and B-frag is the same two b64 Vt reads as before, consumed in
// pairs -> 16 MFMA/tile/wave instead of 32 legacy 16x16x16 (~4x slower each).
extern "C" __global__ __launch_bounds__(256, 2)
void fattn_kernel(const float* __restrict__ Qg, const _Float16* __restrict__ Kh,
                  const _Float16* __restrict__ Vh, const unsigned long long* __restrict__ Wb,
                  float* __restrict__ Og) {
  // tri-buffer: [buf][row][64], 8 KB each; DMA dest lane-contiguous (no pad),
  // bank safety via XOR-granule swizzle
  __shared__ __align__(16) _Float16 Ks[3][NT][64];
  __shared__ __align__(16) _Float16 Vt[3][E_][64];

  const int tid  = threadIdx.x;
  const int wv   = tid >> 6;   // 0..3
  const int lane = tid & 63;
  const int qd   = lane >> 4;
  const int cl   = lane & 15;
  const int sw   = cl & 7;     // reader swizzle key (row & 7)

  // XCD-locality: bid%8 == bh%8 -> all 16 q-blocks of one (b,h) on one XCD
  const int bid = blockIdx.x;
  const int qb  = bid >> 5;
  const int bh  = bid & 31;
  const int h   = bh & (H_ - 1);
  const int b   = bh >> 4;

  const int l0 = qb * MBLK + wv * 32;  // 32 q rows per wave (2 m-tiles)

  // ---- Q fragments (B-operand of S^T = K Q^T), f16, pre-scaled by SCALE2f
  f16x8 qf[2][2];
#pragma unroll
  for (int mt = 0; mt < 2; ++mt) {
    const float* qp = Qg + ((((size_t)b * L_ + (l0 + mt * 16 + cl)) * H_ + h) << 6);
#pragma unroll
    for (int kb = 0; kb < 2; ++kb) {
      const int e0 = qd * 8 + kb * 32;
      f32x4 x = *(const f32x4*)(qp + e0);
      f32x4 y = *(const f32x4*)(qp + e0 + 4);
      x *= SCALE2f;
      y *= SCALE2f;
      H8 u;
      u.i = (i32x4){pkh(x[0], x[1]), pkh(x[2], x[3]), pkh(y[0], y[1]), pkh(y[2], y[3])};
      qf[mt][kb] = u.v;
    }
  }

  // ---- DMA lane constants: lane = 8*row_local + granule_slot
  const int rl  = lane >> 3;       // row within wave-iter (0..7)
  const int gsl = lane & 7;        // granule slot in LDS row
  const int gsw = gsl ^ rl;        // swizzled source granule (row&7 == rl)
  const _Float16* khb = Kh + ((((size_t)b * H_ + h) * S_) << 6);          // [s][e]
  const _Float16* vhb = Vh + ((((size_t)b * H_ + h) << 6) * (size_t)S_);  // [e][s]

  const unsigned long long* wbp = Wb + (((size_t)b * L_ + (l0 + cl)) << 5);

  // stage one tile's K+V via global_load_lds (16 B/lane, 2 wave-iters each)
  auto dma = [&](int buf, int t) {
#pragma unroll
    for (int p = 0; p < 2; ++p) {
      const int r0 = p * 32 + wv * 8;
      const _Float16* ksrc = khb + (((size_t)(t * 64 + r0 + rl)) << 6) + gsw * 8;
      GLOAD_LDS16(ksrc, &Ks[buf][r0][0]);
      const _Float16* vsrc = vhb + (size_t)(r0 + rl) * S_ + t * 64 + gsw * 8;
      GLOAD_LDS16(vsrc, &Vt[buf][r0][0]);
    }
  };

  const f32x4 zero4 = {0.f, 0.f, 0.f, 0.f};
  f32x4 acc[2][4];
#pragma unroll
  for (int mt = 0; mt < 2; ++mt)
#pragma unroll
    for (int et = 0; et < 4; ++et) acc[mt][et] = zero4;
  f32x4 rs4[2] = {zero4, zero4};

  // ---- prologue: regions 0 and 1 (5 VMEM each: mask + 4 gload_lds)
  unsigned long long mwcur = wbp[0];
  dma(0, 0);
  asm volatile("" ::: "memory");  // region boundary
  unsigned long long mwnext = wbp[1];
  dma(1, 1);
  asm volatile("" ::: "memory");

  int bc = 0;  // t % 3
  for (int t = 0; t < NTILES; ++t) {
    // region t landed (tile t K,V,mask); region t+1 (5 ops) stays in flight
    if (t < NTILES - 1)
      asm volatile("s_waitcnt vmcnt(5)" ::: "memory");
    else
      asm volatile("s_waitcnt vmcnt(0)" ::: "memory");
    __builtin_amdgcn_s_barrier();

    // region t+2
    unsigned long long mwnext2 = 0;
    const int bn = (bc == 2) ? 0 : bc + 1;
    if (t + 2 < NTILES) {
      const int b2 = (bn == 2) ? 0 : bn + 1;
      mwnext2 = wbp[t + 2];
      dma(b2, t + 2);
    }
    asm volatile("" ::: "memory");  // region boundary

    // ---- S^T = K Q^T  (A: swizzled Ks rows b128; B: pre-scaled Q regs)
    f32x4 sc[4][2];
#pragma unroll
    for (int nt = 0; nt < 4; ++nt) {
      const _Float16* krow = &Ks[bc][nt * 16 + cl][0];
      const f16x8 a0 = *(const f16x8*)(krow + ((qd ^ sw) << 3));
      const f16x8 a1 = *(const f16x8*)(krow + (((qd + 4) ^ sw) << 3));
#pragma unroll
      for (int mt = 0; mt < 2; ++mt) {
        f32x4 c = zero4;
        c = __builtin_amdgcn_mfma_f32_16x16x32_f16(a0, qf[mt][0], c, 0, 0, 0);
        c = __builtin_amdgcn_mfma_f32_16x16x32_f16(a1, qf[mt][1], c, 0, 0, 0);
        sc[nt][mt] = c;  // q = mt*16+cl, s = nt*16 + qd*4 + r
      }
    }

    // ---- softmax numerator; P packed directly as 16x16x32 A-frag halves
    H8 pa8[2][2];  // [mt][ntp]: slots 0-3 = block 2ntp, slots 4-7 = block 2ntp+1
    if (mwcur == ~0ull) {  // all-attend fast path (Q pre-scaled: exp2 direct)
#pragma unroll
      for (int mt = 0; mt < 2; ++mt)
#pragma unroll
        for (int nt = 0; nt < 4; ++nt) {
          f32x4 p;
#pragma unroll
          for (int r = 0; r < 4; ++r)
            p[r] = __builtin_amdgcn_exp2f(sc[nt][mt][r]);
          rs4[mt] += p;
          H4 u;
          u.h[0] = cvt2(p[0], p[1]);
          u.h[1] = cvt2(p[2], p[3]);
          pa8[mt][nt >> 1].h4[nt & 1] = u.v;
        }
    } else {
      // bit for s = nt*16+qd*4+r sits at p = 16r + 4nt + qd
      const unsigned lo = (unsigned)mwcur;
      const unsigned hi = (unsigned)(mwcur >> 32);
#pragma unroll
      for (int mt = 0; mt < 2; ++mt)
#pragma unroll
        for (int nt = 0; nt < 4; ++nt) {
          const unsigned m0 = lo >> (4 * nt + qd);  // r=0 bit0, r=1 bit16
          const unsigned m1 = hi >> (4 * nt + qd);  // r=2 bit0, r=3 bit16
          f32x4 p;
          p[0] = __builtin_amdgcn_exp2f(sc[nt][mt][0] + ((m0 & 1u)       ? 0.f : MBIAS2f));
          p[1] = __builtin_amdgcn_exp2f(sc[nt][mt][1] + ((m0 & 0x10000u) ? 0.f : MBIAS2f));
          p[2] = __builtin_amdgcn_exp2f(sc[nt][mt][2] + ((m1 & 1u)       ? 0.f : MBIAS2f));
          p[3] = __builtin_amdgcn_exp2f(sc[nt][mt][3] + ((m1 & 0x10000u) ? 0.f : MBIAS2f));
          rs4[mt] += p;
          H4 u;
          u.h[0] = cvt2(p[0], p[1]);
          u.h[1] = cvt2(p[2], p[3]);
          pa8[mt][nt >> 1].h4[nt & 1] = u.v;
        }
    }

    // ---- O += P V at 16x16x32, permuted k (same Vt b64 reads, paired)
#pragma unroll
    for (int ntp = 0; ntp < 2; ++ntp)
#pragma unroll
      for (int et = 0; et < 4; ++et) {
        const _Float16* vrow = &Vt[bc][et * 16 + cl][0];
        H8 bv;
        bv.h4[0] = *(const f16x4*)(vrow + ((((ntp * 4 + (qd >> 1)) ^ sw) << 3) + ((qd & 1) << 2)));
        bv.h4[1] = *(const f16x4*)(vrow + ((((ntp * 4 + 2 + (qd >> 1)) ^ sw) << 3) + ((qd & 1) << 2)));
        acc[0][et] = __builtin_amdgcn_mfma_f32_16x16x32_f16(pa8[0][ntp].v, bv.v, acc[0][et], 0, 0, 0);
        acc[1][et] = __builtin_amdgcn_mfma_f32_16x16x32_f16(pa8[1][ntp].v, bv.v, acc[1][et], 0, 0, 0);
      }

    mwcur = mwnext;
    mwnext = mwnext2;
    bc = bn;
  }

  // ---- epilogue: row-sum reduce, broadcast inv per q-row, store
#pragma unroll
  for (int mt = 0; mt < 2; ++mt) {
    float v = rs4[mt][0] + rs4[mt][1] + rs4[mt][2] + rs4[mt][3];
    v += __shfl_xor(v, 16, 64);
    v += __shfl_xor(v, 32, 64);  // every lane: sum for q = mt*16 + cl
#pragma unroll
    for (int r = 0; r < 4; ++r) {
      const float invq = 1.0f / __shfl(v, qd * 4 + r, 64);
      const int l = l0 + mt * 16 + qd * 4 + r;
      float* op = Og + ((((size_t)b * H_ + h) * L_ + l) << 6) + cl;
#pragma unroll
      for (int et = 0; et < 4; ++et) op[et * 16] = acc[mt][et][r] * invq;
    }
  }
}

extern "C" void kernel_launch(void* const* d_in, const int* in_sizes, int n_in,
                              void* d_out, int out_size, void* d_ws, size_t ws_size,
                              hipStream_t stream) {
  const float* Q = (const float*)d_in[0];
  const float* K = (const float*)d_in[1];
  const float* V = (const float*)d_in[2];
  const float* M = (const float*)d_in[3];
  float* O = (float*)d_out;
  unsigned long long* Wb = (unsigned long long*)d_ws;              // 1 MiB
  _Float16* Khp = (_Float16*)((char*)d_ws + KHOFF);                // 8.39 MB
  _Float16* Vhp = (_Float16*)((char*)d_ws + VHOFF);                // 8.39 MB

  hipLaunchKernelGGL(prep_kernel, dim3(5120), dim3(256), 0, stream, K, V, M, Khp, Vhp, Wb);
  hipLaunchKernelGGL(fattn_kernel, dim3(B_ * H_ * (L_ / MBLK)), dim3(256), 0, stream,
                     Q, Khp, Vhp, Wb, O);
}

// Round 8
// 158.945 us; speedup vs baseline: 1.2052x; 1.0040x over previous
//
#include <hip/hip_runtime.h>

typedef float    f32x4 __attribute__((ext_vector_type(4)));
typedef _Float16 f16x2 __attribute__((ext_vector_type(2)));
typedef _Float16 f16x4 __attribute__((ext_vector_type(4)));
typedef _Float16 f16x8 __attribute__((ext_vector_type(8)));
typedef int      i32x4 __attribute__((ext_vector_type(4)));

namespace {
constexpr int B_ = 2, L_ = 2048, S_ = 2048, H_ = 16, E_ = 64;
constexpr int MBLK = 128;        // q rows per block (4 waves x 32)
constexpr int NT = 64;           // s-tile width
constexpr int NTILES = S_ / NT;  // 32
constexpr int NPAIRS = NTILES / 2;

#define SCALE2f 0.1803368801111204f /* 0.125 * log2(e), folded into Q */
#define MBIAS2f -1.8033688e8f       /* -1e9 * 0.125 * log2(e): exp2 -> exactly 0 */

// ws layout: [0,1MiB) mask bits | Kh f16 [b,h,s,e] 8.39MB | Vh f16 [b,h,e,s] 8.39MB
// mask bit layout inside each u64 (one 64-s chunk): bit p = 16*(s&3) + (s>>2 & 15)
constexpr size_t KHOFF = (size_t)1 << 20;
constexpr size_t VHOFF = KHOFF + (size_t)B_ * H_ * S_ * E_ * 2;

__device__ __forceinline__ f16x2 cvt2(float a, float b) {
  return __builtin_bit_cast(f16x2, __builtin_amdgcn_cvt_pkrtz(a, b));
}
__device__ __forceinline__ int pkh(float a, float b) {
  return __builtin_bit_cast(int, __builtin_amdgcn_cvt_pkrtz(a, b));
}
union H8 { f16x8 v; i32x4 i; f16x4 h4[2]; };
union H4 { f16x4 v; f16x2 h[2]; };

#define GLOAD_LDS16(g, l)                                              \
  __builtin_amdgcn_global_load_lds(                                    \
      (const __attribute__((address_space(1))) void*)(g),              \
      (__attribute__((address_space(3))) void*)(l), 16, 0, 0)
}  // namespace

// ---- fused pre-pass: kcvt [0,2048) | maskpack [2048,4096) | vcvt [4096,5120)
extern "C" __global__ __launch_bounds__(256)
void prep_kernel(const float* __restrict__ Kg, const float* __restrict__ Vg,
                 const float* __restrict__ Mg, _Float16* __restrict__ Kh,
                 _Float16* __restrict__ Vh, unsigned long long* __restrict__ Wb) {
  __shared__ _Float16 T[64][72];
  const int bid = blockIdx.x;
  const int t   = threadIdx.x;

  if (bid < 2048) {
    // K [b,s,h,e] f32 -> Kh [b,h,s,e] f16 (h-gather)
    const int idx = bid * 256 + t;  // 8-e chunk id
    const int j = idx & 7;
    const int h = (idx >> 3) & (H_ - 1);
    const int s = (idx >> 7) & (S_ - 1);
    const int b = idx >> 18;
    const float* src = Kg + ((((size_t)b * S_ + s) * H_ + h) << 6) + j * 8;
    f32x4 x = *(const f32x4*)src, y = *(const f32x4*)(src + 4);
    i32x4 w = {pkh(x[0], x[1]), pkh(x[2], x[3]), pkh(y[0], y[1]), pkh(y[2], y[3])};
    *(i32x4*)(Kh + ((((size_t)b * H_ + h) * S_ + s) << 6) + j * 8) = w;
  } else if (bid < 4096) {
    // mask fp32 -> bits: fully-coalesced 16B/lane loads + ballot + SALU pack.
    // word bit p = 16*(s&3) + (s>>2): ballot_i bit (16j+a) -> word j bit 16i+a.
    const int wv2   = t >> 6;
    const int lane2 = t & 63;
    const size_t wave_id = (size_t)(bid - 2048) * 4 + wv2;   // [0, 8192)
    const float* mp = Mg + wave_id * 1024 + lane2 * 4;
    unsigned long long* wp = Wb + wave_id * 16;
#pragma unroll
    for (int k = 0; k < 4; ++k) {
      const f32x4 x = *(const f32x4*)(mp + k * 256);
      const unsigned long long b0 = __ballot(x[0] > 0.5f);
      const unsigned long long b1 = __ballot(x[1] > 0.5f);
      const unsigned long long b2 = __ballot(x[2] > 0.5f);
      const unsigned long long b3 = __ballot(x[3] > 0.5f);
      if (lane2 < 4) {
        const int sh = lane2 * 16;
        const unsigned long long w =
            ((b0 >> sh) & 0xFFFFull) | (((b1 >> sh) & 0xFFFFull) << 16) |
            (((b2 >> sh) & 0xFFFFull) << 32) | (((b3 >> sh) & 0xFFFFull) << 48);
        wp[k * 4 + lane2] = w;
      }
    }
  } else {
    // V [b,s,h,e] f32 -> Vh [b,h,e,s] f16 (transpose via LDS)
    const int vb = bid - 4096;  // (b,h,st)
    const int st = vb & 31;
    const int h  = (vb >> 5) & (H_ - 1);
    const int b  = vb >> 9;
    const int sl = t >> 2;
    const int e0 = (t & 3) << 4;
    const float* src = Vg + ((((size_t)b * S_ + st * 64 + sl) * H_ + h) << 6) + e0;
#pragma unroll
    for (int i = 0; i < 4; ++i) {
      f32x4 x = *(const f32x4*)(src + i * 4);
#pragma unroll
      for (int c = 0; c < 4; ++c) T[e0 + i * 4 + c][sl] = (_Float16)x[c];
    }
    __syncthreads();
    const int er = t >> 2;
    const int s0 = (t & 3) << 4;
    _Float16* dst = Vh + (((((size_t)b * H_ + h) << 6) + er) * S_) + st * 64 + s0;
    *(i32x4*)dst       = *(const i32x4*)&T[er][s0];
    *(i32x4*)(dst + 8) = *(const i32x4*)&T[er][s0 + 8];
  }
}

// r7 structure + PAIR processing: 2 tiles per barrier interval (quad-buffer,
// 64 KB). Barrier A: pair p's DMA landed (counted vmcnt(10): pair p+1's
// 10 VMEM = 2 mask + 8 gload_lds ride through). Compute both tiles -- one
// unbroken region, so QK(2p+1) interleaves with softmax/PV(2p) (cross-tile
// ILP the per-tile barrier used to forbid). Barrier B: all waves done
// reading pair p -> issue pair p+2 into pair p's buffer slots (race-free).
extern "C" __global__ __launch_bounds__(256, 2)
void fattn_kernel(const float* __restrict__ Qg, const _Float16* __restrict__ Kh,
                  const _Float16* __restrict__ Vh, const unsigned long long* __restrict__ Wb,
                  float* __restrict__ Og) {
  // quad-buffer: tile t lives in buf t&3; DMA dest lane-contiguous (no pad),
  // bank safety via XOR-granule swizzle
  __shared__ __align__(16) _Float16 Ks[4][NT][64];
  __shared__ __align__(16) _Float16 Vt[4][E_][64];

  const int tid  = threadIdx.x;
  const int wv   = tid >> 6;   // 0..3
  const int lane = tid & 63;
  const int qd   = lane >> 4;
  const int cl   = lane & 15;
  const int sw   = cl & 7;     // reader swizzle key (row & 7)

  // XCD-locality: bid%8 == bh%8 -> all 16 q-blocks of one (b,h) on one XCD
  const int bid = blockIdx.x;
  const int qb  = bid >> 5;
  const int bh  = bid & 31;
  const int h   = bh & (H_ - 1);
  const int b   = bh >> 4;

  const int l0 = qb * MBLK + wv * 32;  // 32 q rows per wave (2 m-tiles)

  // ---- Q fragments (B-operand of S^T = K Q^T), f16, pre-scaled by SCALE2f
  f16x8 qf[2][2];
#pragma unroll
  for (int mt = 0; mt < 2; ++mt) {
    const float* qp = Qg + ((((size_t)b * L_ + (l0 + mt * 16 + cl)) * H_ + h) << 6);
#pragma unroll
    for (int kb = 0; kb < 2; ++kb) {
      const int e0 = qd * 8 + kb * 32;
      f32x4 x = *(const f32x4*)(qp + e0);
      f32x4 y = *(const f32x4*)(qp + e0 + 4);
      x *= SCALE2f;
      y *= SCALE2f;
      H8 u;
      u.i = (i32x4){pkh(x[0], x[1]), pkh(x[2], x[3]), pkh(y[0], y[1]), pkh(y[2], y[3])};
      qf[mt][kb] = u.v;
    }
  }

  // ---- DMA lane constants: lane = 8*row_local + granule_slot
  const int rl  = lane >> 3;       // row within wave-iter (0..7)
  const int gsl = lane & 7;        // granule slot in LDS row
  const int gsw = gsl ^ rl;        // swizzled source granule (row&7 == rl)
  const _Float16* khb = Kh + ((((size_t)b * H_ + h) * S_) << 6);          // [s][e]
  const _Float16* vhb = Vh + ((((size_t)b * H_ + h) << 6) * (size_t)S_);  // [e][s]

  const unsigned long long* wbp = Wb + (((size_t)b * L_ + (l0 + cl)) << 5);

  // stage one tile's K+V via global_load_lds (16 B/lane, 2 wave-iters each)
  auto dma = [&](int buf, int t) {
#pragma unroll
    for (int p = 0; p < 2; ++p) {
      const int r0 = p * 32 + wv * 8;
      const _Float16* ksrc = khb + (((size_t)(t * 64 + r0 + rl)) << 6) + gsw * 8;
      GLOAD_LDS16(ksrc, &Ks[buf][r0][0]);
      const _Float16* vsrc = vhb + (size_t)(r0 + rl) * S_ + t * 64 + gsw * 8;
      GLOAD_LDS16(vsrc, &Vt[buf][r0][0]);
    }
  };

  const f32x4 zero4 = {0.f, 0.f, 0.f, 0.f};
  f32x4 acc[2][4];
#pragma unroll
  for (int mt = 0; mt < 2; ++mt)
#pragma unroll
    for (int et = 0; et < 4; ++et) acc[mt][et] = zero4;
  f32x4 rs4[2] = {zero4, zero4};

  // ---- one tile: QK^T -> masked exp2 -> PV (16x16x32 permuted-k)
  auto tilec = [&](int buf, unsigned long long mw) {
    // S^T = K Q^T  (A: swizzled Ks rows b128; B: pre-scaled Q regs)
    f32x4 sc[4][2];
    const _Float16* kb0 = &Ks[buf][0][0];
#pragma unroll
    for (int nt = 0; nt < 4; ++nt) {
      const _Float16* krow = kb0 + (nt * 16 + cl) * 64;
      const f16x8 a0 = *(const f16x8*)(krow + ((qd ^ sw) << 3));
      const f16x8 a1 = *(const f16x8*)(krow + (((qd + 4) ^ sw) << 3));
#pragma unroll
      for (int mt = 0; mt < 2; ++mt) {
        f32x4 c = zero4;
        c = __builtin_amdgcn_mfma_f32_16x16x32_f16(a0, qf[mt][0], c, 0, 0, 0);
        c = __builtin_amdgcn_mfma_f32_16x16x32_f16(a1, qf[mt][1], c, 0, 0, 0);
        sc[nt][mt] = c;  // q = mt*16+cl, s = nt*16 + qd*4 + r
      }
    }

    // softmax numerator; P packed directly as 16x16x32 A-frag halves
    H8 pa8[2][2];  // [mt][ntp]: slots 0-3 = block 2ntp, slots 4-7 = block 2ntp+1
    if (mw == ~0ull) {  // all-attend fast path (Q pre-scaled: exp2 direct)
#pragma unroll
      for (int mt = 0; mt < 2; ++mt)
#pragma unroll
        for (int nt = 0; nt < 4; ++nt) {
          f32x4 p;
#pragma unroll
          for (int r = 0; r < 4; ++r)
            p[r] = __builtin_amdgcn_exp2f(sc[nt][mt][r]);
          rs4[mt] += p;
          H4 u;
          u.h[0] = cvt2(p[0], p[1]);
          u.h[1] = cvt2(p[2], p[3]);
          pa8[mt][nt >> 1].h4[nt & 1] = u.v;
        }
    } else {
      // bit for s = nt*16+qd*4+r sits at p = 16r + 4nt + qd
      const unsigned lo = (unsigned)mw;
      const unsigned hi = (unsigned)(mw >> 32);
#pragma unroll
      for (int mt = 0; mt < 2; ++mt)
#pragma unroll
        for (int nt = 0; nt < 4; ++nt) {
          const unsigned m0 = lo >> (4 * nt + qd);  // r=0 bit0, r=1 bit16
          const unsigned m1 = hi >> (4 * nt + qd);  // r=2 bit0, r=3 bit16
          f32x4 p;
          p[0] = __builtin_amdgcn_exp2f(sc[nt][mt][0] + ((m0 & 1u)       ? 0.f : MBIAS2f));
          p[1] = __builtin_amdgcn_exp2f(sc[nt][mt][1] + ((m0 & 0x10000u) ? 0.f : MBIAS2f));
          p[2] = __builtin_amdgcn_exp2f(sc[nt][mt][2] + ((m1 & 1u)       ? 0.f : MBIAS2f));
          p[3] = __builtin_amdgcn_exp2f(sc[nt][mt][3] + ((m1 & 0x10000u) ? 0.f : MBIAS2f));
          rs4[mt] += p;
          H4 u;
          u.h[0] = cvt2(p[0], p[1]);
          u.h[1] = cvt2(p[2], p[3]);
          pa8[mt][nt >> 1].h4[nt & 1] = u.v;
        }
    }

    // O += P V at 16x16x32, permuted k (same Vt b64 reads, paired)
    const _Float16* vb0 = &Vt[buf][0][0];
#pragma unroll
    for (int ntp = 0; ntp < 2; ++ntp)
#pragma unroll
      for (int et = 0; et < 4; ++et) {
        const _Float16* vrow = vb0 + (et * 16 + cl) * 64;
        H8 bv;
        bv.h4[0] = *(const f16x4*)(vrow + ((((ntp * 4 + (qd >> 1)) ^ sw) << 3) + ((qd & 1) << 2)));
        bv.h4[1] = *(const f16x4*)(vrow + ((((ntp * 4 + 2 + (qd >> 1)) ^ sw) << 3) + ((qd & 1) << 2)));
        acc[0][et] = __builtin_amdgcn_mfma_f32_16x16x32_f16(pa8[0][ntp].v, bv.v, acc[0][et], 0, 0, 0);
        acc[1][et] = __builtin_amdgcn_mfma_f32_16x16x32_f16(pa8[1][ntp].v, bv.v, acc[1][et], 0, 0, 0);
      }
  };

  // ---- prologue: pairs 0 and 1 (10 VMEM each: 2 mask + 8 gload_lds)
  unsigned long long m0 = wbp[0], m1 = wbp[1];
  dma(0, 0);
  dma(1, 1);
  asm volatile("" ::: "memory");  // region boundary
  unsigned long long m2 = wbp[2], m3 = wbp[3];
  dma(2, 2);
  dma(3, 3);
  asm volatile("" ::: "memory");

  for (int p = 0; p < NPAIRS; ++p) {
    // pair p landed; pair p+1 (10 ops) stays in flight
    if (p < NPAIRS - 1)
      asm volatile("s_waitcnt vmcnt(10)" ::: "memory");
    else
      asm volatile("s_waitcnt vmcnt(0)" ::: "memory");
    __builtin_amdgcn_s_barrier();  // A: pair p consumable

    const int b0 = (p & 1) << 1;   // tiles 2p,2p+1 in bufs {b0, b0+1}
    tilec(b0, m0);
    tilec(b0 + 1, m1);

    unsigned long long m4 = 0, m5 = 0;
    if (p + 2 < NPAIRS) {
      __builtin_amdgcn_s_barrier();  // B: all waves done reading pair p
      m4 = wbp[2 * p + 4];
      m5 = wbp[2 * p + 5];
      dma(b0, 2 * p + 4);            // pair p+2 reuses pair p's slots
      dma(b0 + 1, 2 * p + 5);
      asm volatile("" ::: "memory");  // region boundary
    }
    m0 = m2; m1 = m3; m2 = m4; m3 = m5;
  }

  // ---- epilogue: row-sum reduce, broadcast inv per q-row, store
#pragma unroll
  for (int mt = 0; mt < 2; ++mt) {
    float v = rs4[mt][0] + rs4[mt][1] + rs4[mt][2] + rs4[mt][3];
    v += __shfl_xor(v, 16, 64);
    v += __shfl_xor(v, 32, 64);  // every lane: sum for q = mt*16 + cl
#pragma unroll
    for (int r = 0; r < 4; ++r) {
      const float invq = 1.0f / __shfl(v, qd * 4 + r, 64);
      const int l = l0 + mt * 16 + qd * 4 + r;
      float* op = Og + ((((size_t)b * H_ + h) * L_ + l) << 6) + cl;
#pragma unroll
      for (int et = 0; et < 4; ++et) op[et * 16] = acc[mt][et][r] * invq;
    }
  }
}

extern "C" void kernel_launch(void* const* d_in, const int* in_sizes, int n_in,
                              void* d_out, int out_size, void* d_ws, size_t ws_size,
                              hipStream_t stream) {
  const float* Q = (const float*)d_in[0];
  const float* K = (const float*)d_in[1];
  const float* V = (const float*)d_in[2];
  const float* M = (const float*)d_in[3];
  float* O = (float*)d_out;
  unsigned long long* Wb = (unsigned long long*)d_ws;              // 1 MiB
  _Float16* Khp = (_Float16*)((char*)d_ws + KHOFF);                // 8.39 MB
  _Float16* Vhp = (_Float16*)((char*)d_ws + VHOFF);                // 8.39 MB

  hipLaunchKernelGGL(prep_kernel, dim3(5120), dim3(256), 0, stream, K, V, M, Khp, Vhp, Wb);
  hipLaunchKernelGGL(fattn_kernel, dim3(B_ * H_ * (L_ / MBLK)), dim3(256), 0, stream,
                     Q, Khp, Vhp, Wb, O);
}

// Round 9
// 154.885 us; speedup vs baseline: 1.2368x; 1.0262x over previous
//
#include <hip/hip_runtime.h>

typedef float    f32x4 __attribute__((ext_vector_type(4)));
typedef _Float16 f16x2 __attribute__((ext_vector_type(2)));
typedef _Float16 f16x4 __attribute__((ext_vector_type(4)));
typedef _Float16 f16x8 __attribute__((ext_vector_type(8)));
typedef int      i32x4 __attribute__((ext_vector_type(4)));

namespace {
constexpr int B_ = 2, L_ = 2048, S_ = 2048, H_ = 16, E_ = 64;
constexpr int MBLK = 128;        // q rows per block (4 waves x 32)
constexpr int NT = 64;           // s-tile width
constexpr int NTILES = S_ / NT;  // 32
constexpr int NPAIRS = NTILES / 2;

#define SCALE2f 0.1803368801111204f /* 0.125 * log2(e), folded into Q */
#define MBIAS2f -1.8033688e8f       /* -1e9 * 0.125 * log2(e): exp2 -> exactly 0 */

// ws layout: [0,1MiB) mask bits | Kh f16 [b,h,s,e] 8.39MB | Vh f16 [b,h,e,s'] 8.39MB
// mask bit layout inside each u64 (one 64-s chunk): bit p = 16*(s&3) + (s>>2 & 15)
// Vh s-layout: within each 64-s tile, 4-elem chunks permuted pos(8n+4h+q)=8n+2q+h
// so that each PV B-frag (s-chunks 8ntp+qd and 8ntp+qd+4) is one contiguous 16B.
constexpr size_t KHOFF = (size_t)1 << 20;
constexpr size_t VHOFF = KHOFF + (size_t)B_ * H_ * S_ * E_ * 2;

__device__ __forceinline__ f16x2 cvt2(float a, float b) {
  return __builtin_bit_cast(f16x2, __builtin_amdgcn_cvt_pkrtz(a, b));
}
__device__ __forceinline__ int pkh(float a, float b) {
  return __builtin_bit_cast(int, __builtin_amdgcn_cvt_pkrtz(a, b));
}
union H8 { f16x8 v; i32x4 i; f16x4 h4[2]; };
union H4 { f16x4 v; f16x2 h[2]; };

#define GLOAD_LDS16(g, l)                                              \
  __builtin_amdgcn_global_load_lds(                                    \
      (const __attribute__((address_space(1))) void*)(g),              \
      (__attribute__((address_space(3))) void*)(l), 16, 0, 0)
}  // namespace

// ---- fused pre-pass: kcvt [0,2048) | maskpack [2048,4096) | vcvt [4096,5120)
extern "C" __global__ __launch_bounds__(256)
void prep_kernel(const float* __restrict__ Kg, const float* __restrict__ Vg,
                 const float* __restrict__ Mg, _Float16* __restrict__ Kh,
                 _Float16* __restrict__ Vh, unsigned long long* __restrict__ Wb) {
  __shared__ _Float16 T[64][72];
  const int bid = blockIdx.x;
  const int t   = threadIdx.x;

  if (bid < 2048) {
    // K [b,s,h,e] f32 -> Kh [b,h,s,e] f16 (h-gather)
    const int idx = bid * 256 + t;  // 8-e chunk id
    const int j = idx & 7;
    const int h = (idx >> 3) & (H_ - 1);
    const int s = (idx >> 7) & (S_ - 1);
    const int b = idx >> 18;
    const float* src = Kg + ((((size_t)b * S_ + s) * H_ + h) << 6) + j * 8;
    f32x4 x = *(const f32x4*)src, y = *(const f32x4*)(src + 4);
    i32x4 w = {pkh(x[0], x[1]), pkh(x[2], x[3]), pkh(y[0], y[1]), pkh(y[2], y[3])};
    *(i32x4*)(Kh + ((((size_t)b * H_ + h) * S_ + s) << 6) + j * 8) = w;
  } else if (bid < 4096) {
    // mask fp32 -> bits: fully-coalesced 16B/lane loads + ballot + SALU pack.
    // word bit p = 16*(s&3) + (s>>2): ballot_i bit (16j+a) -> word j bit 16i+a.
    const int wv2   = t >> 6;
    const int lane2 = t & 63;
    const size_t wave_id = (size_t)(bid - 2048) * 4 + wv2;   // [0, 8192)
    const float* mp = Mg + wave_id * 1024 + lane2 * 4;
    unsigned long long* wp = Wb + wave_id * 16;
#pragma unroll
    for (int k = 0; k < 4; ++k) {
      const f32x4 x = *(const f32x4*)(mp + k * 256);
      const unsigned long long b0 = __ballot(x[0] > 0.5f);
      const unsigned long long b1 = __ballot(x[1] > 0.5f);
      const unsigned long long b2 = __ballot(x[2] > 0.5f);
      const unsigned long long b3 = __ballot(x[3] > 0.5f);
      if (lane2 < 4) {
        const int sh = lane2 * 16;
        const unsigned long long w =
            ((b0 >> sh) & 0xFFFFull) | (((b1 >> sh) & 0xFFFFull) << 16) |
            (((b2 >> sh) & 0xFFFFull) << 32) | (((b3 >> sh) & 0xFFFFull) << 48);
        wp[k * 4 + lane2] = w;
      }
    }
  } else {
    // V [b,s,h,e] f32 -> Vh [b,h,e,s'] f16 (transpose via LDS), s-chunks
    // interleaved within each 64-s tile: dst pos 4u+k holds source chunk
    // {C, C+4, C+1, C+5}[k], C = 8*(u>>1) + 2*(u&1)  (pos(8n+4h+q)=8n+2q+h).
    const int vb = bid - 4096;  // (b,h,st)
    const int st = vb & 31;
    const int h  = (vb >> 5) & (H_ - 1);
    const int b  = vb >> 9;
    const int sl = t >> 2;
    const int e0 = (t & 3) << 4;
    const float* src = Vg + ((((size_t)b * S_ + st * 64 + sl) * H_ + h) << 6) + e0;
#pragma unroll
    for (int i = 0; i < 4; ++i) {
      f32x4 x = *(const f32x4*)(src + i * 4);
#pragma unroll
      for (int c = 0; c < 4; ++c) T[e0 + i * 4 + c][sl] = (_Float16)x[c];
    }
    __syncthreads();
    const int er = t >> 2;
    const int u  = t & 3;
    const int C  = ((u >> 1) << 3) + ((u & 1) << 1);
    _Float16* dst = Vh + (((((size_t)b * H_ + h) << 6) + er) * S_) + st * 64 + u * 16;
    H8 w;
    w.h4[0] = *(const f16x4*)&T[er][(C) * 4];
    w.h4[1] = *(const f16x4*)&T[er][(C + 4) * 4];
    *(i32x4*)dst = w.i;
    w.h4[0] = *(const f16x4*)&T[er][(C + 1) * 4];
    w.h4[1] = *(const f16x4*)&T[er][(C + 5) * 4];
    *(i32x4*)(dst + 8) = w.i;
  }
}

// r8 structure (pair processing, quad-buffer, counted vmcnt) + interleaved Vt:
// PV B-frags are now single b128 reads (8 per tile/wave, was 16 b64). Slot
// algebra: B-frag elem j at granule ntp*4+qd = s 32ntp+16*(j>=4)+4qd+(j&3),
// identical to the P fragments' sigma -> numerics unchanged.
extern "C" __global__ __launch_bounds__(256, 2)
void fattn_kernel(const float* __restrict__ Qg, const _Float16* __restrict__ Kh,
                  const _Float16* __restrict__ Vh, const unsigned long long* __restrict__ Wb,
                  float* __restrict__ Og) {
  // quad-buffer: tile t lives in buf t&3; DMA dest lane-contiguous (no pad),
  // bank safety via XOR-granule swizzle
  __shared__ __align__(16) _Float16 Ks[4][NT][64];
  __shared__ __align__(16) _Float16 Vt[4][E_][64];

  const int tid  = threadIdx.x;
  const int wv   = tid >> 6;   // 0..3
  const int lane = tid & 63;
  const int qd   = lane >> 4;
  const int cl   = lane & 15;
  const int sw   = cl & 7;     // reader swizzle key (row & 7)

  // XCD-locality: bid%8 == bh%8 -> all 16 q-blocks of one (b,h) on one XCD
  const int bid = blockIdx.x;
  const int qb  = bid >> 5;
  const int bh  = bid & 31;
  const int h   = bh & (H_ - 1);
  const int b   = bh >> 4;

  const int l0 = qb * MBLK + wv * 32;  // 32 q rows per wave (2 m-tiles)

  // ---- Q fragments (B-operand of S^T = K Q^T), f16, pre-scaled by SCALE2f
  f16x8 qf[2][2];
#pragma unroll
  for (int mt = 0; mt < 2; ++mt) {
    const float* qp = Qg + ((((size_t)b * L_ + (l0 + mt * 16 + cl)) * H_ + h) << 6);
#pragma unroll
    for (int kb = 0; kb < 2; ++kb) {
      const int e0 = qd * 8 + kb * 32;
      f32x4 x = *(const f32x4*)(qp + e0);
      f32x4 y = *(const f32x4*)(qp + e0 + 4);
      x *= SCALE2f;
      y *= SCALE2f;
      H8 u;
      u.i = (i32x4){pkh(x[0], x[1]), pkh(x[2], x[3]), pkh(y[0], y[1]), pkh(y[2], y[3])};
      qf[mt][kb] = u.v;
    }
  }

  // ---- DMA lane constants: lane = 8*row_local + granule_slot
  const int rl  = lane >> 3;       // row within wave-iter (0..7)
  const int gsl = lane & 7;        // granule slot in LDS row
  const int gsw = gsl ^ rl;        // swizzled source granule (row&7 == rl)
  const _Float16* khb = Kh + ((((size_t)b * H_ + h) * S_) << 6);          // [s][e]
  const _Float16* vhb = Vh + ((((size_t)b * H_ + h) << 6) * (size_t)S_);  // [e][s']

  const unsigned long long* wbp = Wb + (((size_t)b * L_ + (l0 + cl)) << 5);

  // stage one tile's K+V via global_load_lds (16 B/lane, 2 wave-iters each)
  auto dma = [&](int buf, int t) {
#pragma unroll
    for (int p = 0; p < 2; ++p) {
      const int r0 = p * 32 + wv * 8;
      const _Float16* ksrc = khb + (((size_t)(t * 64 + r0 + rl)) << 6) + gsw * 8;
      GLOAD_LDS16(ksrc, &Ks[buf][r0][0]);
      const _Float16* vsrc = vhb + (size_t)(r0 + rl) * S_ + t * 64 + gsw * 8;
      GLOAD_LDS16(vsrc, &Vt[buf][r0][0]);
    }
  };

  const f32x4 zero4 = {0.f, 0.f, 0.f, 0.f};
  f32x4 acc[2][4];
#pragma unroll
  for (int mt = 0; mt < 2; ++mt)
#pragma unroll
    for (int et = 0; et < 4; ++et) acc[mt][et] = zero4;
  f32x4 rs4[2] = {zero4, zero4};

  // ---- one tile: QK^T -> masked exp2 -> PV (16x16x32 permuted-k)
  auto tilec = [&](int buf, unsigned long long mw) {
    // S^T = K Q^T  (A: swizzled Ks rows b128; B: pre-scaled Q regs)
    f32x4 sc[4][2];
    const _Float16* kb0 = &Ks[buf][0][0];
#pragma unroll
    for (int nt = 0; nt < 4; ++nt) {
      const _Float16* krow = kb0 + (nt * 16 + cl) * 64;
      const f16x8 a0 = *(const f16x8*)(krow + ((qd ^ sw) << 3));
      const f16x8 a1 = *(const f16x8*)(krow + (((qd + 4) ^ sw) << 3));
#pragma unroll
      for (int mt = 0; mt < 2; ++mt) {
        f32x4 c = zero4;
        c = __builtin_amdgcn_mfma_f32_16x16x32_f16(a0, qf[mt][0], c, 0, 0, 0);
        c = __builtin_amdgcn_mfma_f32_16x16x32_f16(a1, qf[mt][1], c, 0, 0, 0);
        sc[nt][mt] = c;  // q = mt*16+cl, s = nt*16 + qd*4 + r
      }
    }

    // softmax numerator; P packed directly as 16x16x32 A-frag halves
    H8 pa8[2][2];  // [mt][ntp]: slots 0-3 = block 2ntp, slots 4-7 = block 2ntp+1
    if (mw == ~0ull) {  // all-attend fast path (Q pre-scaled: exp2 direct)
#pragma unroll
      for (int mt = 0; mt < 2; ++mt)
#pragma unroll
        for (int nt = 0; nt < 4; ++nt) {
          f32x4 p;
#pragma unroll
          for (int r = 0; r < 4; ++r)
            p[r] = __builtin_amdgcn_exp2f(sc[nt][mt][r]);
          rs4[mt] += p;
          H4 u;
          u.h[0] = cvt2(p[0], p[1]);
          u.h[1] = cvt2(p[2], p[3]);
          pa8[mt][nt >> 1].h4[nt & 1] = u.v;
        }
    } else {
      // bit for s = nt*16+qd*4+r sits at p = 16r + 4nt + qd
      const unsigned lo = (unsigned)mw;
      const unsigned hi = (unsigned)(mw >> 32);
#pragma unroll
      for (int mt = 0; mt < 2; ++mt)
#pragma unroll
        for (int nt = 0; nt < 4; ++nt) {
          const unsigned m0 = lo >> (4 * nt + qd);  // r=0 bit0, r=1 bit16
          const unsigned m1 = hi >> (4 * nt + qd);  // r=2 bit0, r=3 bit16
          f32x4 p;
          p[0] = __builtin_amdgcn_exp2f(sc[nt][mt][0] + ((m0 & 1u)       ? 0.f : MBIAS2f));
          p[1] = __builtin_amdgcn_exp2f(sc[nt][mt][1] + ((m0 & 0x10000u) ? 0.f : MBIAS2f));
          p[2] = __builtin_amdgcn_exp2f(sc[nt][mt][2] + ((m1 & 1u)       ? 0.f : MBIAS2f));
          p[3] = __builtin_amdgcn_exp2f(sc[nt][mt][3] + ((m1 & 0x10000u) ? 0.f : MBIAS2f));
          rs4[mt] += p;
          H4 u;
          u.h[0] = cvt2(p[0], p[1]);
          u.h[1] = cvt2(p[2], p[3]);
          pa8[mt][nt >> 1].h4[nt & 1] = u.v;
        }
    }

    // O += P V at 16x16x32: interleaved Vt -> one b128 B-frag per MFMA
    const _Float16* vb0 = &Vt[buf][0][0];
#pragma unroll
    for (int ntp = 0; ntp < 2; ++ntp)
#pragma unroll
      for (int et = 0; et < 4; ++et) {
        const _Float16* vrow = vb0 + (et * 16 + cl) * 64;
        const f16x8 bv = *(const f16x8*)(vrow + (((ntp * 4 + qd) ^ sw) << 3));
        acc[0][et] = __builtin_amdgcn_mfma_f32_16x16x32_f16(pa8[0][ntp].v, bv, acc[0][et], 0, 0, 0);
        acc[1][et] = __builtin_amdgcn_mfma_f32_16x16x32_f16(pa8[1][ntp].v, bv, acc[1][et], 0, 0, 0);
      }
  };

  // ---- prologue: pairs 0 and 1 (10 VMEM each: 2 mask + 8 gload_lds)
  unsigned long long m0 = wbp[0], m1 = wbp[1];
  dma(0, 0);
  dma(1, 1);
  asm volatile("" ::: "memory");  // region boundary
  unsigned long long m2 = wbp[2], m3 = wbp[3];
  dma(2, 2);
  dma(3, 3);
  asm volatile("" ::: "memory");

  for (int p = 0; p < NPAIRS; ++p) {
    // pair p landed; pair p+1 (10 ops) stays in flight
    if (p < NPAIRS - 1)
      asm volatile("s_waitcnt vmcnt(10)" ::: "memory");
    else
      asm volatile("s_waitcnt vmcnt(0)" ::: "memory");
    __builtin_amdgcn_s_barrier();  // A: pair p consumable

    const int b0 = (p & 1) << 1;   // tiles 2p,2p+1 in bufs {b0, b0+1}
    tilec(b0, m0);
    tilec(b0 + 1, m1);

    unsigned long long m4 = 0, m5 = 0;
    if (p + 2 < NPAIRS) {
      __builtin_amdgcn_s_barrier();  // B: all waves done reading pair p
      m4 = wbp[2 * p + 4];
      m5 = wbp[2 * p + 5];
      dma(b0, 2 * p + 4);            // pair p+2 reuses pair p's slots
      dma(b0 + 1, 2 * p + 5);
      asm volatile("" ::: "memory");  // region boundary
    }
    m0 = m2; m1 = m3; m2 = m4; m3 = m5;
  }

  // ---- epilogue: row-sum reduce, broadcast inv per q-row, store
#pragma unroll
  for (int mt = 0; mt < 2; ++mt) {
    float v = rs4[mt][0] + rs4[mt][1] + rs4[mt][2] + rs4[mt][3];
    v += __shfl_xor(v, 16, 64);
    v += __shfl_xor(v, 32, 64);  // every lane: sum for q = mt*16 + cl
#pragma unroll
    for (int r = 0; r < 4; ++r) {
      const float invq = 1.0f / __shfl(v, qd * 4 + r, 64);
      const int l = l0 + mt * 16 + qd * 4 + r;
      float* op = Og + ((((size_t)b * H_ + h) * L_ + l) << 6) + cl;
#pragma unroll
      for (int et = 0; et < 4; ++et) op[et * 16] = acc[mt][et][r] * invq;
    }
  }
}

extern "C" void kernel_launch(void* const* d_in, const int* in_sizes, int n_in,
                              void* d_out, int out_size, void* d_ws, size_t ws_size,
                              hipStream_t stream) {
  const float* Q = (const float*)d_in[0];
  const float* K = (const float*)d_in[1];
  const float* V = (const float*)d_in[2];
  const float* M = (const float*)d_in[3];
  float* O = (float*)d_out;
  unsigned long long* Wb = (unsigned long long*)d_ws;              // 1 MiB
  _Float16* Khp = (_Float16*)((char*)d_ws + KHOFF);                // 8.39 MB
  _Float16* Vhp = (_Float16*)((char*)d_ws + VHOFF);                // 8.39 MB

  hipLaunchKernelGGL(prep_kernel, dim3(5120), dim3(256), 0, stream, K, V, M, Khp, Vhp, Wb);
  hipLaunchKernelGGL(fattn_kernel, dim3(B_ * H_ * (L_ / MBLK)), dim3(256), 0, stream,
                     Q, Khp, Vhp, Wb, O);
}